// Round 2
// baseline (338.526 us; speedup 1.0000x reference)
//
#include <hip/hip_runtime.h>
#include <hip/hip_bf16.h>

#define S 1024
#define D 64
#define BH 64
#define SCALE 0.125f

typedef __attribute__((ext_vector_type(8))) short short8;
typedef __attribute__((ext_vector_type(16))) float f32x16;

// packed bf16x2 via hardware cvt (RNE), 1 inst per 2 elements
static __device__ __forceinline__ unsigned cvt_pk_bf16(float lo, float hi) {
  unsigned r;
  asm("v_cvt_pk_bf16_f32 %0, %1, %2" : "=v"(r) : "v"(lo), "v"(hi));
  return r;
}

static __device__ __forceinline__ short8 pack8(const float* f) {
  union { unsigned u[4]; short8 s; } r;
  r.u[0] = cvt_pk_bf16(f[0], f[1]);
  r.u[1] = cvt_pk_bf16(f[2], f[3]);
  r.u[2] = cvt_pk_bf16(f[4], f[5]);
  r.u[3] = cvt_pk_bf16(f[6], f[7]);
  return r.s;
}

static __device__ __forceinline__ short8 load_frag8(const float* p) {
  float4 a = *(const float4*)p;
  float4 b = *(const float4*)(p + 4);
  float f[8] = {a.x, a.y, a.z, a.w, b.x, b.y, b.z, b.w};
  return pack8(f);
}

// Phase 1: rcp[bh,kcol] = 1/sum_q exp(masked score); also bit-pack mask:
// packed[(bh*S+qrow)*32 + kt] bit c = mask[qrow][kt*32+c].
// Block 256 thr (4 waves), 32 kcols per block, wave covers 8 q-tiles.
template <bool PACK>
__global__ __launch_bounds__(256) void colsum_kernel(
    const float* __restrict__ q, const float* __restrict__ k,
    const int* __restrict__ mask, float* __restrict__ rcp,
    unsigned* __restrict__ packed) {
  int tid = threadIdx.x;
  int wave = tid >> 6, lane = tid & 63;
  int l31 = lane & 31, hi = lane >> 5;
  int r8 = lane >> 3, c8 = lane & 7;
  int kb = blockIdx.x * 32;
  int bh = blockIdx.y;
  const float* qh = q + (size_t)bh * S * D;
  const float* kh = k + (size_t)bh * S * D;
  const int* mh = mask + (size_t)bh * S * S;

  __shared__ unsigned wrow[4][32];
  __shared__ float red[4][32];

  short8 bfrag[4];
  const float* kp = kh + (size_t)(kb + l31) * D + hi * 8;
#pragma unroll
  for (int s = 0; s < 4; ++s) bfrag[s] = load_frag8(kp + s * 16);

  float colpart = 0.f;
  for (int it = 0; it < 8; ++it) {
    int q0 = it * 128 + wave * 32;
    // vectorized mask tile load: lane covers row r8+8j, cols c8*4..+3
    int4 m4[4];
#pragma unroll
    for (int j = 0; j < 4; ++j)
      m4[j] = *(const int4*)(mh + (size_t)(q0 + r8 + 8 * j) * S + kb + c8 * 4);

    const float* qp = qh + (size_t)(q0 + l31) * D + hi * 8;
    short8 afrag[4];
#pragma unroll
    for (int s = 0; s < 4; ++s) afrag[s] = load_frag8(qp + s * 16);
    f32x16 acc = {};
#pragma unroll
    for (int s = 0; s < 4; ++s)
      acc = __builtin_amdgcn_mfma_f32_32x32x16_bf16(afrag[s], bfrag[s], acc, 0, 0, 0);

    // assemble per-row 32-bit mask words (or-butterfly across the 8 lanes of a row)
#pragma unroll
    for (int j = 0; j < 4; ++j) {
      unsigned nib = (m4[j].x ? 1u : 0u) | (m4[j].y ? 2u : 0u) |
                     (m4[j].z ? 4u : 0u) | (m4[j].w ? 8u : 0u);
      unsigned w = nib << (c8 * 4);
      w |= __shfl_xor(w, 1, 64);
      w |= __shfl_xor(w, 2, 64);
      w |= __shfl_xor(w, 4, 64);
      if (c8 == 0) {
        wrow[wave][r8 + 8 * j] = w;
        if (PACK)
          packed[((size_t)bh * S + q0 + r8 + 8 * j) * 32 + blockIdx.x] = w;
      }
    }
#pragma unroll
    for (int r = 0; r < 16; ++r) {
      int crow = (r & 3) + 8 * (r >> 2) + 4 * hi;
      unsigned mw = wrow[wave][crow];  // LDS broadcast per half-wave
      float e = __expf(acc[r] * SCALE);
      colpart += ((mw >> l31) & 1u) ? e : 0.0f;
    }
  }
  // lanes l and l+32 hold the same column
  colpart += __shfl_xor(colpart, 32, 64);
  if (lane < 32) red[wave][lane] = colpart;
  __syncthreads();
  if (tid < 32) {
    float t = red[0][tid] + red[1][tid] + red[2][tid] + red[3][tid];
    rcp[(size_t)bh * S + kb + tid] = 1.0f / t;
  }
}

// Phase 2: recompute scores, normalize, write attn + out.
// Block 512 thr (8 waves): wave = (kw*4 + qw); qw picks 32-q-row subtile,
// kw splits the 32 k-tiles in half. Partial out reduced through LDS.
template <bool PACKED>
__global__ __launch_bounds__(512, 4) void attn_out_kernel(
    const float* __restrict__ q, const float* __restrict__ k,
    const float* __restrict__ v, const int* __restrict__ mask,
    const unsigned* __restrict__ packed, const float* __restrict__ rcp,
    float* __restrict__ outp, float* __restrict__ attnp) {
  int tid = threadIdx.x;
  int wave = tid >> 6, lane = tid & 63;
  int l31 = lane & 31, hi = lane >> 5;
  int qw = wave & 3, kw = wave >> 2;
  int bh = blockIdx.y;
  int qb = blockIdx.x * 128 + qw * 32;
  const float* qh = q + (size_t)bh * S * D;
  const float* kh = k + (size_t)bh * S * D;
  const float* vh = v + (size_t)bh * S * D;
  const int* mh = mask + (size_t)bh * S * S;
  const float* rch = rcp + (size_t)bh * S;
  float* ah = attnp + (size_t)bh * S * S;

  __shared__ float sm[8][32][33];      // per-wave P tile (pad 33: conflict-free)
  __shared__ unsigned wlds[8][32][16]; // per-wave packed-mask words

  if (PACKED) {
    const unsigned* pp =
        packed + ((size_t)bh * S + qb + (lane >> 1)) * 32 + kw * 16 + (lane & 1) * 8;
#pragma unroll
    for (int jj = 0; jj < 2; ++jj)
      *(int4*)&wlds[wave][lane >> 1][(lane & 1) * 8 + jj * 4] = *(const int4*)(pp + jj * 4);
  }

  short8 afrag[4];
  const float* qp = qh + (size_t)(qb + l31) * D + hi * 8;
#pragma unroll
  for (int s = 0; s < 4; ++s) afrag[s] = load_frag8(qp + s * 16);

  f32x16 oacc0 = {}, oacc1 = {};

  for (int kt = kw * 16; kt < kw * 16 + 16; ++kt) {
    int kb2 = kt * 32;
    const float* kp = kh + (size_t)(kb2 + l31) * D + hi * 8;
    short8 bfrag[4];
#pragma unroll
    for (int s = 0; s < 4; ++s) bfrag[s] = load_frag8(kp + s * 16);
    f32x16 acc = {};
#pragma unroll
    for (int s = 0; s < 4; ++s)
      acc = __builtin_amdgcn_mfma_f32_32x32x16_bf16(afrag[s], bfrag[s], acc, 0, 0, 0);

    int kcol = kb2 + l31;
    float rc = rch[kcol];
#pragma unroll
    for (int r = 0; r < 16; ++r) {
      int ql = (r & 3) + 8 * (r >> 2) + 4 * hi;
      int qrow = qb + ql;
      unsigned bit;
      if (PACKED) {
        unsigned mw = wlds[wave][ql][kt - kw * 16];  // same addr per half-wave
        bit = (mw >> l31) & 1u;
      } else {
        bit = mh[(size_t)qrow * S + kcol] ? 1u : 0u;
      }
      float e = bit ? __expf(acc[r] * SCALE) * rc : 0.0f;
      ah[(size_t)qrow * S + kcol] = e;  // coalesced fp32 store
      sm[wave][ql][l31] = e;
    }

    // PV: out[q][d] += P[q][kk] * v[kk][d]
#pragma unroll
    for (int s2 = 0; s2 < 2; ++s2) {
      float pv[8];
      const float* smrow = &sm[wave][l31][0];
#pragma unroll
      for (int e = 0; e < 8; ++e) pv[e] = smrow[s2 * 16 + hi * 8 + e];
      short8 pa = pack8(pv);
      const float* vp = vh + (size_t)(kb2 + s2 * 16 + hi * 8) * D + l31;
      float v0[8], v1[8];
#pragma unroll
      for (int e = 0; e < 8; ++e) {
        v0[e] = vp[(size_t)e * D];
        v1[e] = vp[(size_t)e * D + 32];
      }
      short8 vf0 = pack8(v0), vf1 = pack8(v1);
      oacc0 = __builtin_amdgcn_mfma_f32_32x32x16_bf16(pa, vf0, oacc0, 0, 0, 0);
      oacc1 = __builtin_amdgcn_mfma_f32_32x32x16_bf16(pa, vf1, oacc1, 0, 0, 0);
    }
  }

  // combine the two k-halves: waves 4-7 dump partials, waves 0-3 add + store
  __syncthreads();
  float* red = &sm[0][0][0];  // 8448 floats, need 255*33+32 <= 8448
  if (wave >= 4) {
    float* dst = red + (size_t)((wave - 4) * 64 + lane) * 33;
#pragma unroll
    for (int r = 0; r < 16; ++r) {
      dst[r] = oacc0[r];
      dst[16 + r] = oacc1[r];
    }
  }
  __syncthreads();
  if (wave < 4) {
    const float* src = red + (size_t)(wave * 64 + lane) * 33;
#pragma unroll
    for (int r = 0; r < 16; ++r) {
      oacc0[r] += src[r];
      oacc1[r] += src[16 + r];
    }
    float* oh = outp + (size_t)bh * S * D;
#pragma unroll
    for (int r = 0; r < 16; ++r) {
      int ql = (r & 3) + 8 * (r >> 2) + 4 * hi;
      oh[(size_t)(qb + ql) * D + l31] = oacc0[r];
      oh[(size_t)(qb + ql) * D + 32 + l31] = oacc1[r];
    }
  }
}

extern "C" void kernel_launch(void* const* d_in, const int* in_sizes, int n_in,
                              void* d_out, int out_size, void* d_ws, size_t ws_size,
                              hipStream_t stream) {
  const float* q = (const float*)d_in[0];
  const float* k = (const float*)d_in[1];
  const float* v = (const float*)d_in[2];
  const int* mask = (const int*)d_in[3];
  float* outp = (float*)d_out;
  float* attnp = outp + (size_t)BH * S * D;  // out first, then attn
  float* rcp = (float*)d_ws;                 // BH*S floats = 256 KB
  size_t rcp_bytes = (size_t)BH * S * 4;
  size_t packed_bytes = (size_t)BH * S * 32 * 4;  // 8.4 MB

  if (ws_size >= rcp_bytes + packed_bytes) {
    unsigned* packed = (unsigned*)((char*)d_ws + rcp_bytes);
    colsum_kernel<true><<<dim3(32, BH), 256, 0, stream>>>(q, k, mask, rcp, packed);
    attn_out_kernel<true><<<dim3(8, BH), 512, 0, stream>>>(q, k, v, mask, packed, rcp,
                                                           outp, attnp);
  } else {
    colsum_kernel<false><<<dim3(32, BH), 256, 0, stream>>>(q, k, mask, rcp, nullptr);
    attn_out_kernel<false><<<dim3(8, BH), 512, 0, stream>>>(q, k, v, mask, nullptr, rcp,
                                                            outp, attnp);
  }
}